// Round 3
// baseline (34.036 us; speedup 1.0000x reference)
//
#include <hip/hip_runtime.h>

// Problem constants (B=1024, I=128, H=512, O=16)
#define B_DIM 1024
#define I_DIM 128
#define H_DIM 512
#define O_CNT 16
#define S1_BLOCKS 256   // 16 options x 16 sample-stripes of 64
#define U_BLOCKS  2048  // 8192 (o,h) row-dots, one per wave

// Full 64-lane butterfly reduction (wave = 64 on CDNA4).
__device__ __forceinline__ float wave_reduce_sum(float v) {
#pragma unroll
    for (int off = 32; off > 0; off >>= 1)
        v += __shfl_xor(v, off, 64);
    return v;
}

// ---------------- fast path: 2 dispatches ----------------
// D1 (heterogeneous grid):
//   blocks [0, 256): s1-blocks. Block (o, stripe) computes
//     s1[b,:] = state[b,:] @ W1[o]  for each b in its 64-sample stripe with option[b]==o.
//     256 threads; thread t owns the h-pair (2t, 2t+1). W1 re-reads hit L2/L3.
//   blocks [256, 2304): u-blocks. One wave per (o,h) row:
//     u[o*H+h] = dot(W2[o,h,:], W3[o,:])   -- the 16 MB HBM stream.
// s1-blocks are FIRST so their L2-limited work overlaps the u HBM stream.
__global__ __launch_bounds__(256) void k_phase1(const float* __restrict__ W1,
                                                const float* __restrict__ W2,
                                                const float* __restrict__ W3,
                                                const float* __restrict__ state,
                                                const int* __restrict__ option,
                                                float* __restrict__ u,
                                                float* __restrict__ s1)
{
    const int bid = blockIdx.x;
    const int tid = threadIdx.x;

    if (bid >= S1_BLOCKS) {
        // ---- u part: full-chip HBM stream of W2 ----
        const int wid  = ((bid - S1_BLOCKS) << 2) + (tid >> 6);  // [0, 8192)
        const int lane = tid & 63;
        const int o    = wid >> 9;
        const float4* row = (const float4*)(W2 + (size_t)wid * H_DIM);
        const float4* w3  = (const float4*)(W3 + (size_t)o * H_DIM);
        float4 a0 = row[lane], a1 = row[lane + 64];
        float4 b0 = w3[lane],  b1 = w3[lane + 64];
        float acc = a0.x*b0.x + a0.y*b0.y + a0.z*b0.z + a0.w*b0.w
                  + a1.x*b1.x + a1.y*b1.y + a1.z*b1.z + a1.w*b1.w;
        acc = wave_reduce_sum(acc);
        if (lane == 0) u[wid] = acc;
        return;
    }

    // ---- s1 part ----
    const int o    = bid >> 4;         // option
    const int base = (bid & 15) << 6;  // stripe * 64
    const float2* W1o = (const float2*)(W1 + (size_t)o * I_DIM * H_DIM);
    float2* s1p = (float2*)s1;

    // Process matching samples in groups of up to 4 (one W1[o] pass per group;
    // expected exactly one group of ~4). Named regs to avoid dynamic indexing.
    int g0 = 0, g1 = 0, g2 = 0, g3 = 0, cnt = 0;

    auto flush = [&](int n) {
        const int b0 = g0;
        const int b1 = (n > 1) ? g1 : g0;
        const int b2 = (n > 2) ? g2 : g0;
        const int b3 = (n > 3) ? g3 : g0;
        const float* st0 = state + (size_t)b0 * I_DIM;
        const float* st1 = state + (size_t)b1 * I_DIM;
        const float* st2 = state + (size_t)b2 * I_DIM;
        const float* st3 = state + (size_t)b3 * I_DIM;
        float2 a0 = {0.f, 0.f}, a1 = a0, a2 = a0, a3 = a0;
#pragma unroll 4
        for (int i = 0; i < I_DIM; ++i) {
            float2 w = W1o[(size_t)i * (H_DIM / 2) + tid];
            float v0 = st0[i], v1 = st1[i], v2 = st2[i], v3 = st3[i];
            a0.x += v0 * w.x; a0.y += v0 * w.y;
            a1.x += v1 * w.x; a1.y += v1 * w.y;
            a2.x += v2 * w.x; a2.y += v2 * w.y;
            a3.x += v3 * w.x; a3.y += v3 * w.y;
        }
        s1p[(size_t)b0 * (H_DIM / 2) + tid] = a0;
        if (n > 1) s1p[(size_t)b1 * (H_DIM / 2) + tid] = a1;
        if (n > 2) s1p[(size_t)b2 * (H_DIM / 2) + tid] = a2;
        if (n > 3) s1p[(size_t)b3 * (H_DIM / 2) + tid] = a3;
    };

    for (int t = 0; t < 64; ++t) {
        if (option[base + t] == o) {
            const int b = base + t;
            g0 = (cnt == 0) ? b : g0;
            g1 = (cnt == 1) ? b : g1;
            g2 = (cnt == 2) ? b : g2;
            g3 = (cnt == 3) ? b : g3;
            if (++cnt == 4) { flush(4); cnt = 0; }
        }
    }
    if (cnt > 0) flush(cnt);
}

// D2: out[b] = dot(s1[b,:], u[opt[b],:]) over H=512. One wave per sample.
__global__ __launch_bounds__(256) void k_out2(const float* __restrict__ s1,
                                              const float* __restrict__ u,
                                              const int* __restrict__ option,
                                              float* __restrict__ out)
{
    const int b    = (blockIdx.x * 256 + threadIdx.x) >> 6;  // [0, 1024)
    const int lane = threadIdx.x & 63;
    const int o    = option[b];
    const float4* xr = (const float4*)(s1 + (size_t)b * H_DIM);
    const float4* ur = (const float4*)(u + (size_t)o * H_DIM);
    float4 x0 = xr[lane], x1 = xr[lane + 64];
    float4 u0 = ur[lane], u1 = ur[lane + 64];
    float acc = x0.x*u0.x + x0.y*u0.y + x0.z*u0.z + x0.w*u0.w
              + x1.x*u1.x + x1.y*u1.y + x1.z*u1.z + x1.w*u1.w;
    acc = wave_reduce_sum(acc);
    if (lane == 0) out[b] = acc;
}

// ---------------- fallback path: proven 3-dispatch (13.7 us) ----------------
__global__ __launch_bounds__(256) void k_w2w3(const float* __restrict__ W2,
                                              const float* __restrict__ W3,
                                              float* __restrict__ u) {
    const int wid  = (blockIdx.x * 256 + threadIdx.x) >> 6;
    const int lane = threadIdx.x & 63;
    const int o = wid >> 9;
    const float4* row = (const float4*)(W2 + (size_t)wid * H_DIM);
    const float4* w3  = (const float4*)(W3 + (size_t)o * H_DIM);
    float4 a0 = row[lane], a1 = row[lane + 64];
    float4 b0 = w3[lane],  b1 = w3[lane + 64];
    float acc = a0.x*b0.x + a0.y*b0.y + a0.z*b0.z + a0.w*b0.w
              + a1.x*b1.x + a1.y*b1.y + a1.z*b1.z + a1.w*b1.w;
    acc = wave_reduce_sum(acc);
    if (lane == 0) u[wid] = acc;
}

__global__ __launch_bounds__(256) void k_w1u(const float* __restrict__ W1,
                                             const float* __restrict__ u,
                                             float* __restrict__ v) {
    const int wid  = (blockIdx.x * 256 + threadIdx.x) >> 6;
    const int lane = threadIdx.x & 63;
    const int o = wid >> 7;
    const float4* row = (const float4*)(W1 + (size_t)wid * H_DIM);
    const float4* uo  = (const float4*)(u + (size_t)o * H_DIM);
    float4 a0 = row[lane], a1 = row[lane + 64];
    float4 b0 = uo[lane],  b1 = uo[lane + 64];
    float acc = a0.x*b0.x + a0.y*b0.y + a0.z*b0.z + a0.w*b0.w
              + a1.x*b1.x + a1.y*b1.y + a1.z*b1.z + a1.w*b1.w;
    acc = wave_reduce_sum(acc);
    if (lane == 0) v[wid] = acc;
}

__global__ __launch_bounds__(256) void k_out(const float* __restrict__ state,
                                             const int* __restrict__ option,
                                             const float* __restrict__ v,
                                             float* __restrict__ out) {
    const int b    = (blockIdx.x * 256 + threadIdx.x) >> 6;
    const int lane = threadIdx.x & 63;
    const int o = option[b];
    const float2* srow = (const float2*)(state + (size_t)b * I_DIM);
    const float2* vrow = (const float2*)(v + (size_t)o * I_DIM);
    float2 s = srow[lane];
    float2 w = vrow[lane];
    float acc = s.x * w.x + s.y * w.y;
    acc = wave_reduce_sum(acc);
    if (lane == 0) out[b] = acc;
}

extern "C" void kernel_launch(void* const* d_in, const int* in_sizes, int n_in,
                              void* d_out, int out_size, void* d_ws, size_t ws_size,
                              hipStream_t stream) {
    const float* state  = (const float*)d_in[0];
    // d_in[1] = action, unused by the reference forward.
    const float* W1     = (const float*)d_in[2];
    const float* W2     = (const float*)d_in[3];
    const float* W3     = (const float*)d_in[4];
    const int*   option = (const int*)d_in[5];
    float* out = (float*)d_out;

    float* u = (float*)d_ws;                              // 16*512 f32 = 32 KiB
    const size_t need = (size_t)(O_CNT * H_DIM) * 4       // u
                      + (size_t)B_DIM * H_DIM * 4;        // s1: 2 MiB

    if (ws_size >= need) {
        float* s1 = u + O_CNT * H_DIM;
        // D1: 256 s1-blocks (first, long L2 phase) + 2048 u-blocks (HBM stream).
        k_phase1<<<S1_BLOCKS + U_BLOCKS, 256, 0, stream>>>(W1, W2, W3, state, option, u, s1);
        // D2: 1024 waves of H=512 dots, everything L2-hot.
        k_out2<<<B_DIM / 4, 256, 0, stream>>>(s1, u, option, out);
    } else {
        // Fallback: proven 3-dispatch pipeline.
        float* v = u + O_CNT * H_DIM;                     // 8 KiB
        k_w2w3<<<2048, 256, 0, stream>>>(W2, W3, u);
        k_w1u<<<512, 256, 0, stream>>>(W1, u, v);
        k_out<<<256, 256, 0, stream>>>(state, option, v, out);
    }
}

// Round 4
// 18.203 us; speedup vs baseline: 1.8698x; 1.8698x over previous
//
#include <hip/hip_runtime.h>

// Problem constants (B=1024, I=128, H=512, O=16)
#define B_DIM 1024
#define I_DIM 128
#define H_DIM 512
#define O_CNT 16
#define NCHUNK 32            // h-chunks per option
#define CH 16                // h rows per chunk (NCHUNK*CH == H_DIM)

// Full 64-lane butterfly reduction (wave = 64 on CDNA4).
__device__ __forceinline__ float wave_reduce_sum(float v) {
#pragma unroll
    for (int off = 32; off > 0; off >>= 1)
        v += __shfl_xor(v, off, 64);
    return v;
}

// D1: block (o, c) — fully independent unit of work, no cross-block deps.
//   u_c[r]   = dot(W2[o, c*CH+r, :], W3[o, :])        r in [0,CH)    (32 KB W2 slice)
//   y_c[i]   = sum_r W1[o, i, c*CH+r] * u_c[r]        i in [0,128)   (8 KB W1 slice)
//   for b with opt[b]==o: partial[c*B + b] = dot(state[b,:], y_c)
// Every partial slot (c,b) has exactly one writer: block (opt[b], c). Deterministic.
__global__ __launch_bounds__(256) void k_fused(const float* __restrict__ W1,
                                               const float* __restrict__ W2,
                                               const float* __restrict__ W3,
                                               const float* __restrict__ state,
                                               const int* __restrict__ option,
                                               float* __restrict__ partial)
{
    const int o    = blockIdx.x >> 5;      // [0,16)
    const int c    = blockIdx.x & 31;      // [0,32)
    const int tid  = threadIdx.x;          // [0,256)
    const int w    = tid >> 6;             // wave [0,4)
    const int lane = tid & 63;

    __shared__ float u_s[CH];
    __shared__ float y_s[I_DIM];
    __shared__ int   opt_s[B_DIM];

    // Stage option[] (4 coalesced int loads per thread).
#pragma unroll
    for (int g = 0; g < 4; ++g) opt_s[tid + 256 * g] = option[tid + 256 * g];

    // ---- Phase A: u-chunk. Wave w owns rows w*4 .. w*4+3 of the chunk. ----
    const float4* w3 = (const float4*)(W3 + (size_t)o * H_DIM);
    const float4 b0 = w3[lane], b1 = w3[lane + 64];
#pragma unroll
    for (int j = 0; j < 4; ++j) {
        const int r = w * 4 + j;                       // row within chunk
        const int h = c * CH + r;                      // global h
        const float4* rp = (const float4*)(W2 + ((size_t)o * H_DIM + h) * H_DIM);
        float4 a0 = rp[lane], a1 = rp[lane + 64];
        float acc = a0.x*b0.x + a0.y*b0.y + a0.z*b0.z + a0.w*b0.w
                  + a1.x*b1.x + a1.y*b1.y + a1.z*b1.z + a1.w*b1.w;
        acc = wave_reduce_sum(acc);
        if (lane == 0) u_s[r] = acc;
    }
    __syncthreads();

    // ---- Phase B: y-chunk. Thread i<128 computes y[i] over the CH=16 h's. ----
    if (tid < I_DIM) {
        const float4* wp = (const float4*)(W1 + ((size_t)o * I_DIM + tid) * H_DIM + c * CH);
        float y = 0.f;
#pragma unroll
        for (int q = 0; q < 4; ++q) {
            float4 wv = wp[q];
            y += wv.x * u_s[q*4+0] + wv.y * u_s[q*4+1]
               + wv.z * u_s[q*4+2] + wv.w * u_s[q*4+3];
        }
        y_s[tid] = y;
    }
    __syncthreads();

    // ---- Phase C: partial outs. Wave w scans samples [w*256, (w+1)*256). ----
    const float2 yv = *(const float2*)(y_s + 2 * lane);   // b64 read, conflict-free
#pragma unroll
    for (int g = 0; g < 4; ++g) {
        const int bbase = w * 256 + g * 64;
        const int m = opt_s[bbase + lane];
        unsigned long long mask = __ballot(m == o);
        while (mask) {
            const int bit = __ffsll((long long)mask) - 1;
            mask &= mask - 1;
            const int b = bbase + bit;
            const float2* sr = (const float2*)(state + (size_t)b * I_DIM);
            float2 s = sr[lane];
            float acc = s.x * yv.x + s.y * yv.y;
            acc = wave_reduce_sum(acc);
            if (lane == 0) partial[(size_t)c * B_DIM + b] = acc;
        }
    }
}

// D2: out[b] = sum_c partial[c*B + b]. Coalesced: fixed c -> consecutive b per lane.
__global__ __launch_bounds__(256) void k_reduce(const float* __restrict__ partial,
                                                float* __restrict__ out)
{
    const int b = blockIdx.x * 256 + threadIdx.x;      // [0,1024)
    float acc = 0.f;
#pragma unroll
    for (int c = 0; c < NCHUNK; ++c)
        acc += partial[(size_t)c * B_DIM + b];
    out[b] = acc;
}

// ---------------- fallback: proven 3-dispatch (13.7 us) ----------------
__global__ __launch_bounds__(256) void k_w2w3(const float* __restrict__ W2,
                                              const float* __restrict__ W3,
                                              float* __restrict__ u) {
    const int wid  = (blockIdx.x * 256 + threadIdx.x) >> 6;
    const int lane = threadIdx.x & 63;
    const int o = wid >> 9;
    const float4* row = (const float4*)(W2 + (size_t)wid * H_DIM);
    const float4* w3  = (const float4*)(W3 + (size_t)o * H_DIM);
    float4 a0 = row[lane], a1 = row[lane + 64];
    float4 b0 = w3[lane],  b1 = w3[lane + 64];
    float acc = a0.x*b0.x + a0.y*b0.y + a0.z*b0.z + a0.w*b0.w
              + a1.x*b1.x + a1.y*b1.y + a1.z*b1.z + a1.w*b1.w;
    acc = wave_reduce_sum(acc);
    if (lane == 0) u[wid] = acc;
}
__global__ __launch_bounds__(256) void k_w1u(const float* __restrict__ W1,
                                             const float* __restrict__ u,
                                             float* __restrict__ v) {
    const int wid  = (blockIdx.x * 256 + threadIdx.x) >> 6;
    const int lane = threadIdx.x & 63;
    const int o = wid >> 7;
    const float4* row = (const float4*)(W1 + (size_t)wid * H_DIM);
    const float4* uo  = (const float4*)(u + (size_t)o * H_DIM);
    float4 a0 = row[lane], a1 = row[lane + 64];
    float4 b0 = uo[lane],  b1 = uo[lane + 64];
    float acc = a0.x*b0.x + a0.y*b0.y + a0.z*b0.z + a0.w*b0.w
              + a1.x*b1.x + a1.y*b1.y + a1.z*b1.z + a1.w*b1.w;
    acc = wave_reduce_sum(acc);
    if (lane == 0) v[wid] = acc;
}
__global__ __launch_bounds__(256) void k_out(const float* __restrict__ state,
                                             const int* __restrict__ option,
                                             const float* __restrict__ v,
                                             float* __restrict__ out) {
    const int b    = (blockIdx.x * 256 + threadIdx.x) >> 6;
    const int lane = threadIdx.x & 63;
    const int o = option[b];
    const float2* srow = (const float2*)(state + (size_t)b * I_DIM);
    const float2* vrow = (const float2*)(v + (size_t)o * I_DIM);
    float2 s = srow[lane];
    float2 w = vrow[lane];
    float acc = s.x * w.x + s.y * w.y;
    acc = wave_reduce_sum(acc);
    if (lane == 0) out[b] = acc;
}

extern "C" void kernel_launch(void* const* d_in, const int* in_sizes, int n_in,
                              void* d_out, int out_size, void* d_ws, size_t ws_size,
                              hipStream_t stream) {
    const float* state  = (const float*)d_in[0];
    // d_in[1] = action, unused by the reference forward.
    const float* W1     = (const float*)d_in[2];
    const float* W2     = (const float*)d_in[3];
    const float* W3     = (const float*)d_in[4];
    const int*   option = (const int*)d_in[5];
    float* out = (float*)d_out;

    const size_t need = (size_t)NCHUNK * B_DIM * sizeof(float);   // 128 KiB

    if (ws_size >= need) {
        float* partial = (float*)d_ws;
        // D1: 16 options x 32 chunks = 512 blocks; every block streams a
        // disjoint 32KB W2 slice + 8KB W1 slice -> full-chip HBM BW.
        k_fused<<<O_CNT * NCHUNK, 256, 0, stream>>>(W1, W2, W3, state, option, partial);
        // D2: 1024 sums of 32 floats.
        k_reduce<<<B_DIM / 256, 256, 0, stream>>>(partial, out);
    } else {
        float* u = (float*)d_ws;
        float* v = u + O_CNT * H_DIM;
        k_w2w3<<<2048, 256, 0, stream>>>(W2, W3, u);
        k_w1u<<<512, 256, 0, stream>>>(W1, u, v);
        k_out<<<256, 256, 0, stream>>>(state, option, v, out);
    }
}

// Round 5
// 12.766 us; speedup vs baseline: 2.6660x; 1.4258x over previous
//
#include <hip/hip_runtime.h>

// Problem constants (B=1024, I=128, H=512, O=16)
#define B_DIM 1024
#define I_DIM 128
#define H_DIM 512
#define O_CNT 16
#define NCH 16     // h-chunks per option
#define CH 32      // h rows per chunk (NCH*CH == H_DIM)

// Full 64-lane butterfly reduction (wave = 64 on CDNA4).
__device__ __forceinline__ float wave_reduce_sum(float v) {
#pragma unroll
    for (int off = 32; off > 0; off >>= 1)
        v += __shfl_xor(v, off, 64);
    return v;
}

// D1: block (o, c) — pure streaming, no sample work.
//   u_s[r] = dot(W2[o, c*CH+r, :], W3[o, :])      r in [0,CH)   (64 KB contiguous W2 slice)
//   y[o,c,i] = sum_r W1[o, i, c*CH+r] * u_s[r]    i in [0,128)  (16 KB line-aligned W1 slice)
// Every y slot has exactly one writer. v[o] = sum_c y[o,c,:] is reconstructed in D2.
__global__ __launch_bounds__(512) void k_y(const float* __restrict__ W1,
                                           const float* __restrict__ W2,
                                           const float* __restrict__ W3,
                                           float* __restrict__ y)
{
    const int o    = blockIdx.x >> 4;    // [0,16)
    const int c    = blockIdx.x & 15;    // [0,16)
    const int tid  = threadIdx.x;        // [0,512)
    const int w    = tid >> 6;           // wave [0,8)
    const int lane = tid & 63;
    const int h0   = c * CH;

    __shared__ float u_s[CH];

    // Phase A: u-chunk. Wave w owns rows w*4 .. w*4+3 (32 rows total).
    const float4* w3 = (const float4*)(W3 + (size_t)o * H_DIM);
    const float4 b0 = w3[lane], b1 = w3[lane + 64];
#pragma unroll
    for (int j = 0; j < 4; ++j) {
        const int r = w * 4 + j;
        const float4* rp = (const float4*)(W2 + ((size_t)o * H_DIM + h0 + r) * H_DIM);
        float4 a0 = rp[lane], a1 = rp[lane + 64];
        float acc = a0.x*b0.x + a0.y*b0.y + a0.z*b0.z + a0.w*b0.w
                  + a1.x*b1.x + a1.y*b1.y + a1.z*b1.z + a1.w*b1.w;
        acc = wave_reduce_sum(acc);
        if (lane == 0) u_s[r] = acc;
    }
    __syncthreads();

    // Phase B: y-chunk. Thread i<128 reads its 128 B row-slice of W1 (full cache
    // lines, 128B-aligned since h0*4 = c*128 bytes) and contracts with u_s
    // (all-broadcast LDS reads).
    if (tid < I_DIM) {
        const float4* wp = (const float4*)(W1 + ((size_t)o * I_DIM + tid) * H_DIM + h0);
        float yv = 0.f;
#pragma unroll
        for (int q = 0; q < 8; ++q) {
            float4 wv = wp[q];
            yv += wv.x * u_s[4*q+0] + wv.y * u_s[4*q+1]
                + wv.z * u_s[4*q+2] + wv.w * u_s[4*q+3];
        }
        y[((size_t)o * NCH + c) * I_DIM + tid] = yv;
    }
}

// D2: one wave per sample. v[opt[b]] is summed from the 16 chunk-partials
// inline (L2-hot, coalesced 512 B per load across the wave), then dotted
// with state[b].
__global__ __launch_bounds__(256) void k_out_y(const float* __restrict__ state,
                                               const int* __restrict__ option,
                                               const float* __restrict__ y,
                                               float* __restrict__ out)
{
    const int b    = (blockIdx.x * 256 + threadIdx.x) >> 6;  // [0,1024)
    const int lane = threadIdx.x & 63;
    const int o    = option[b];
    const float2  s  = ((const float2*)(state + (size_t)b * I_DIM))[lane];
    const float2* yb = (const float2*)(y + (size_t)o * NCH * I_DIM);
    float2 acc2 = {0.f, 0.f};
#pragma unroll
    for (int q = 0; q < NCH; ++q) {
        float2 yv = yb[q * (I_DIM / 2) + lane];
        acc2.x += s.x * yv.x;
        acc2.y += s.y * yv.y;
    }
    float acc = wave_reduce_sum(acc2.x + acc2.y);
    if (lane == 0) out[b] = acc;
}

// ---------------- fallback: proven 3-dispatch (13.7 us) ----------------
__global__ __launch_bounds__(256) void k_w2w3(const float* __restrict__ W2,
                                              const float* __restrict__ W3,
                                              float* __restrict__ u) {
    const int wid  = (blockIdx.x * 256 + threadIdx.x) >> 6;
    const int lane = threadIdx.x & 63;
    const int o = wid >> 9;
    const float4* row = (const float4*)(W2 + (size_t)wid * H_DIM);
    const float4* w3  = (const float4*)(W3 + (size_t)o * H_DIM);
    float4 a0 = row[lane], a1 = row[lane + 64];
    float4 b0 = w3[lane],  b1 = w3[lane + 64];
    float acc = a0.x*b0.x + a0.y*b0.y + a0.z*b0.z + a0.w*b0.w
              + a1.x*b1.x + a1.y*b1.y + a1.z*b1.z + a1.w*b1.w;
    acc = wave_reduce_sum(acc);
    if (lane == 0) u[wid] = acc;
}
__global__ __launch_bounds__(256) void k_w1u(const float* __restrict__ W1,
                                             const float* __restrict__ u,
                                             float* __restrict__ v) {
    const int wid  = (blockIdx.x * 256 + threadIdx.x) >> 6;
    const int lane = threadIdx.x & 63;
    const int o = wid >> 7;
    const float4* row = (const float4*)(W1 + (size_t)wid * H_DIM);
    const float4* uo  = (const float4*)(u + (size_t)o * H_DIM);
    float4 a0 = row[lane], a1 = row[lane + 64];
    float4 b0 = uo[lane],  b1 = uo[lane + 64];
    float acc = a0.x*b0.x + a0.y*b0.y + a0.z*b0.z + a0.w*b0.w
              + a1.x*b1.x + a1.y*b1.y + a1.z*b1.z + a1.w*b1.w;
    acc = wave_reduce_sum(acc);
    if (lane == 0) v[wid] = acc;
}
__global__ __launch_bounds__(256) void k_out(const float* __restrict__ state,
                                             const int* __restrict__ option,
                                             const float* __restrict__ v,
                                             float* __restrict__ out) {
    const int b    = (blockIdx.x * 256 + threadIdx.x) >> 6;
    const int lane = threadIdx.x & 63;
    const int o = option[b];
    const float2* srow = (const float2*)(state + (size_t)b * I_DIM);
    const float2* vrow = (const float2*)(v + (size_t)o * I_DIM);
    float2 s = srow[lane];
    float2 w = vrow[lane];
    float acc = s.x * w.x + s.y * w.y;
    acc = wave_reduce_sum(acc);
    if (lane == 0) out[b] = acc;
}

extern "C" void kernel_launch(void* const* d_in, const int* in_sizes, int n_in,
                              void* d_out, int out_size, void* d_ws, size_t ws_size,
                              hipStream_t stream) {
    const float* state  = (const float*)d_in[0];
    // d_in[1] = action, unused by the reference forward.
    const float* W1     = (const float*)d_in[2];
    const float* W2     = (const float*)d_in[3];
    const float* W3     = (const float*)d_in[4];
    const int*   option = (const int*)d_in[5];
    float* out = (float*)d_out;

    const size_t need = (size_t)O_CNT * NCH * I_DIM * sizeof(float);  // 128 KiB

    if (ws_size >= need) {
        float* y = (float*)d_ws;
        // D1: 256 blocks x 512 threads; each block streams a disjoint 64KB W2
        // slice + 16KB line-aligned W1 slice -> full aggregate HBM BW.
        k_y<<<O_CNT * NCH, 512, 0, stream>>>(W1, W2, W3, y);
        // D2: one wave per sample; y is L2-hot.
        k_out_y<<<B_DIM / 4, 256, 0, stream>>>(state, option, y, out);
    } else {
        float* u = (float*)d_ws;
        float* v = u + O_CNT * H_DIM;
        k_w2w3<<<2048, 256, 0, stream>>>(W2, W3, u);
        k_w1u<<<512, 256, 0, stream>>>(W1, u, v);
        k_out<<<256, 256, 0, stream>>>(state, option, v, out);
    }
}